// Round 2
// baseline (218.451 us; speedup 1.0000x reference)
//
#include <hip/hip_runtime.h>
#include <math.h>

#define NCLU 10
#define D    64
#define NSLOT 4096

typedef unsigned int   u32;
typedef unsigned short u16;

typedef __attribute__((ext_vector_type(8))) short  bf16x8;
typedef __attribute__((ext_vector_type(4))) float  f32x4;

__device__ __forceinline__ u16 f2bf_rne(float f) {
    u32 u = __float_as_uint(f);
    return (u16)((u + 0x7fffu + ((u >> 16) & 1u)) >> 16);
}

__device__ __forceinline__ bf16x8 pack8(float4 a, float4 b) {
    bf16x8 r;
    r[0] = (short)f2bf_rne(a.x); r[1] = (short)f2bf_rne(a.y);
    r[2] = (short)f2bf_rne(a.z); r[3] = (short)f2bf_rne(a.w);
    r[4] = (short)f2bf_rne(b.x); r[5] = (short)f2bf_rne(b.y);
    r[6] = (short)f2bf_rne(b.z); r[7] = (short)f2bf_rne(b.w);
    return r;
}

__device__ __forceinline__ float wred(float v) {
#pragma unroll
    for (int off = 32; off > 0; off >>= 1) v += __shfl_xor(v, off);
    return v;
}

// Load a 64x64 f32 weight matrix as MFMA A-fragments (bf16): a[mt][kt], lane (quad,lc)
// holds W[16*mt+lc][kt*32 + quad*8 .. +7]. 32 VGPRs total per wave.
__device__ __forceinline__ void load_afrags64(bf16x8 a[4][2], const float* __restrict__ W,
                                              int lc, int quad) {
#pragma unroll
    for (int mt = 0; mt < 4; ++mt)
#pragma unroll
        for (int kt = 0; kt < 2; ++kt) {
            const float* p = W + (16 * mt + lc) * 64 + kt * 32 + quad * 8;
            a[mt][kt] = pack8(*(const float4*)p, *(const float4*)(p + 4));
        }
}

// Same for a 64x128 matrix, covering k-tiles ktbase..ktbase+1 (half of K=128).
__device__ __forceinline__ void load_afrags128(bf16x8 a[4][2], const float* __restrict__ W,
                                               int ktbase, int lc, int quad) {
#pragma unroll
    for (int mt = 0; mt < 4; ++mt)
#pragma unroll
        for (int kt = 0; kt < 2; ++kt) {
            const float* p = W + (16 * mt + lc) * 128 + (ktbase + kt) * 32 + quad * 8;
            a[mt][kt] = pack8(*(const float4*)p, *(const float4*)(p + 4));
        }
}

// B-fragment from f32 LDS state X[n][k] (row stride in floats): lane holds
// X[n=lc][ktglob*32 + quad*8 .. +7], zeros for n>=NCLU.
__device__ __forceinline__ bf16x8 bfrag(const float* __restrict__ xbase, int xstride,
                                        int lc, int quad, int ktglob) {
    if (lc < NCLU) {
        const float* p = xbase + lc * xstride + ktglob * 32 + quad * 8;
        return pack8(*(const float4*)p, *(const float4*)(p + 4));
    }
    bf16x8 z;
#pragma unroll
    for (int j = 0; j < 8; ++j) z[j] = 0;
    return z;
}

// D = A(64xK) @ X^T (+bias, opt relu) written to out[n=lc][ooff + dim].
// D layout: col=lane&15 (n), row=quad*4+reg (dim within 16-tile).
__device__ __forceinline__ void mm_apply(const bf16x8 a[4][2], const float* __restrict__ xbase,
                                         int xstride, int ktbase,
                                         float* __restrict__ obase, int ostride, int ooff,
                                         const float* __restrict__ bias, bool do_relu,
                                         int lc, int quad) {
    f32x4 acc[4];
#pragma unroll
    for (int mt = 0; mt < 4; ++mt) acc[mt] = (f32x4){0.f, 0.f, 0.f, 0.f};
#pragma unroll
    for (int kt = 0; kt < 2; ++kt) {
        bf16x8 b = bfrag(xbase, xstride, lc, quad, ktbase + kt);
#pragma unroll
        for (int mt = 0; mt < 4; ++mt)
            acc[mt] = __builtin_amdgcn_mfma_f32_16x16x32_bf16(a[mt][kt], b, acc[mt], 0, 0, 0);
    }
    if (lc < NCLU) {
#pragma unroll
        for (int mt = 0; mt < 4; ++mt) {
            float4 o;
            o.x = acc[mt][0]; o.y = acc[mt][1]; o.z = acc[mt][2]; o.w = acc[mt][3];
            if (bias) {
                float4 bv = *(const float4*)(bias + 16 * mt + 4 * quad);
                o.x += bv.x; o.y += bv.y; o.z += bv.z; o.w += bv.w;
            }
            if (do_relu) {
                o.x = fmaxf(o.x, 0.f); o.y = fmaxf(o.y, 0.f);
                o.z = fmaxf(o.z, 0.f); o.w = fmaxf(o.w, 0.f);
            }
            *(float4*)(obase + lc * ostride + ooff + 16 * mt + 4 * quad) = o;
        }
    }
}

// ---------------- Phase 1: MFMA weight-stationary slot-attention ----------------
// (unchanged — isolating the phase-2 change this round)
__global__ __launch_bounds__(640, 3) void phase1_kernel(
    const float* __restrict__ cc0,
    const float* __restrict__ Wk, const float* __restrict__ bk,
    const float* __restrict__ Wq, const float* __restrict__ bq,
    const float* __restrict__ Wv, const float* __restrict__ bv,
    const float* __restrict__ cc_g, const float* __restrict__ cc_b,
    const float* __restrict__ W_ih, const float* __restrict__ W_hh,
    const float* __restrict__ b_ih, const float* __restrict__ b_hh,
    const float* __restrict__ ln_g, const float* __restrict__ ln_b,
    const float* __restrict__ W1, const float* __restrict__ b1,
    const float* __restrict__ W2, const float* __restrict__ b2,
    float* __restrict__ cc_out)
{
    const int t = threadIdx.x;
    const int w = t >> 6;
    const int i = t & 63;
    const int quad = i >> 4;
    const int lc   = i & 15;

    __shared__ float ccl[NCLU][68];
    __shared__ float xl[NCLU][68];
    __shared__ float kl[NCLU][68];
    __shared__ float vl[NCLU][68];
    __shared__ float ql[NCLU][68];
    __shared__ float ul[NCLU][68];
    __shared__ float hl[NCLU][68];
    __shared__ float dl9[NCLU][68];
    __shared__ float dl8[NCLU][68];
    __shared__ float tl[NCLU][132];
    __shared__ float gl[6][NCLU][68];
    __shared__ float al[NCLU][12];

    const float g_cc = cc_g[i], b_cc = cc_b[i];
    const float g_ln = ln_g[i], b_ln = ln_b[i];

    // ---- weight fragments (per-wave role; arrays are 32 VGPRs each) ----
    bf16x8 afrA[4][2], afrB[4][2];
#pragma unroll
    for (int mt = 0; mt < 4; ++mt)
#pragma unroll
        for (int kt = 0; kt < 2; ++kt) {
#pragma unroll
            for (int j = 0; j < 8; ++j) { afrA[mt][kt][j] = 0; afrB[mt][kt][j] = 0; }
        }

    const float* biasA = nullptr;   // bias pointer for afrA's matmul
    if (w == 0)      { load_afrags64(afrA, Wq, lc, quad);                    biasA = bq; }
    else if (w <= 3) { load_afrags64(afrA, W_ih + (w - 1) * 64 * 64, lc, quad); biasA = b_ih + (w - 1) * 64; }
    else if (w <= 6) { load_afrags64(afrA, W_hh + (w - 4) * 64 * 64, lc, quad); biasA = b_hh + (w - 4) * 64; }
    else if (w == 7) { load_afrags64(afrA, Wk, lc, quad); }   // swapped to W1-lo after kv
    else if (w == 8) { load_afrags64(afrA, Wv, lc, quad);     // swapped to W1-hi after kv
                       load_afrags128(afrB, W2, 2, lc, quad); }
    else             { load_afrags128(afrA, W2, 0, lc, quad); biasA = b2; }

    float c = cc0[w * 64 + i];
    ccl[w][i] = c;
    __syncthreads();

    // ---- k, v from original cluster_centers ----
    if (w == 7)      mm_apply(afrA, &ccl[0][0], 68, 0, &kl[0][0], 68, 0, bk, false, lc, quad);
    else if (w == 8) mm_apply(afrA, &ccl[0][0], 68, 0, &vl[0][0], 68, 0, bv, false, lc, quad);
    __syncthreads();

    // swap w7/w8 to W1 halves (one-time global frag loads, overlap with iter-1 front)
    if (w == 7)      { load_afrags64(afrA, W1, lc, quad);            biasA = b1; }
    else if (w == 8) { load_afrags64(afrA, W1 + 64 * 64, lc, quad);  biasA = b1 + 64; }

    for (int it = 0; it < 3; ++it) {
        // ---- LN(cc) ----
        {
            float s1 = wred(c), s2 = wred(c * c);
            float mu = s1 * (1.f / 64.f);
            float va = s2 * (1.f / 64.f) - mu * mu;
            xl[w][i] = (c - mu) * rsqrtf(va + 1e-5f) * g_cc + b_cc;
        }
        __syncthreads();

        // ---- q (w0, xl) concurrent with gh gates (w4-6, prev ccl) ----
        if (w == 0)
            mm_apply(afrA, &xl[0][0], 68, 0, &ql[0][0], 68, 0, biasA, false, lc, quad);
        else if (w >= 4 && w <= 6)
            mm_apply(afrA, &ccl[0][0], 68, 0, &gl[w - 1][0][0], 68, 0, biasA, false, lc, quad);
        __syncthreads();

        // ---- attn[n][m] = temp * <k[n], q[m]>, wave n, lanes m<10 ----
        if (i < NCLU) {
            const float4* kf = (const float4*)&kl[w][0];
            const float4* qf = (const float4*)&ql[i][0];
            float a0 = 0.f, a1 = 0.f, a2 = 0.f, a3 = 0.f;
#pragma unroll
            for (int jj = 0; jj < 16; ++jj) {
                float4 kv = kf[jj], qv = qf[jj];
                a0 += kv.x * qv.x; a1 += kv.y * qv.y; a2 += kv.z * qv.z; a3 += kv.w * qv.w;
            }
            al[w][i] = ((a0 + a1) + (a2 + a3)) * 0.125f;
        }
        __syncthreads();

        // ---- softmax over axis 0 + EPS ----
        if (t < NCLU) {
            float mx = -1e30f;
#pragma unroll
            for (int nn = 0; nn < NCLU; ++nn) mx = fmaxf(mx, al[nn][t]);
            float e[NCLU]; float s = 0.f;
#pragma unroll
            for (int nn = 0; nn < NCLU; ++nn) { e[nn] = __expf(al[nn][t] - mx); s += e[nn]; }
            float inv = 1.f / s;
#pragma unroll
            for (int nn = 0; nn < NCLU; ++nn) al[nn][t] = e[nn] * inv + 1e-8f;
        }
        __syncthreads();
        // ---- row renormalize ----
        if (t < NCLU) {
            float s = 0.f;
#pragma unroll
            for (int m = 0; m < NCLU; ++m) s += al[t][m];
            float inv = 1.f / s;
#pragma unroll
            for (int m = 0; m < NCLU; ++m) al[t][m] *= inv;
        }
        __syncthreads();

        // ---- updates = attn @ v ----
        {
            float u = 0.f;
#pragma unroll
            for (int m = 0; m < NCLU; ++m) u += al[w][m] * vl[m][i];
            ul[w][i] = u;
        }
        __syncthreads();

        // ---- gi gates (w1-3, from ul) ----
        if (w >= 1 && w <= 3)
            mm_apply(afrA, &ul[0][0], 68, 0, &gl[w - 1][0][0], 68, 0, biasA, false, lc, quad);
        __syncthreads();

        // ---- GRU combine + MLP LN (wave == row) ----
        {
            float ir = gl[0][w][i], iz = gl[1][w][i], inn = gl[2][w][i];
            float hr = gl[3][w][i], hz = gl[4][w][i], hn = gl[5][w][i];
            float r = 1.f / (1.f + __expf(-(ir + hr)));
            float z = 1.f / (1.f + __expf(-(iz + hz)));
            float nn2 = tanhf(inn + r * hn);
            c = (1.f - z) * nn2 + z * c;

            float s1 = wred(c), s2 = wred(c * c);
            float mu = s1 * (1.f / 64.f);
            float va = s2 * (1.f / 64.f) - mu * mu;
            hl[w][i] = (c - mu) * rsqrtf(va + 1e-5f) * g_ln + b_ln;
        }
        __syncthreads();

        // ---- hidden = relu(h @ W1^T + b1): w7 -> tl[:,0:64], w8 -> tl[:,64:128] ----
        if (w == 7)
            mm_apply(afrA, &hl[0][0], 68, 0, &tl[0][0], 132, 0, biasA, true, lc, quad);
        else if (w == 8)
            mm_apply(afrA, &hl[0][0], 68, 0, &tl[0][0], 132, 64, biasA, true, lc, quad);
        __syncthreads();

        // ---- delta = hidden @ W2^T + b2: w9 k[0:64] (+b2), w8 k[64:128] ----
        if (w == 9)
            mm_apply(afrA, &tl[0][0], 132, 0, &dl9[0][0], 68, 0, biasA, false, lc, quad);
        else if (w == 8)
            mm_apply(afrB, &tl[0][0], 132, 2, &dl8[0][0], 68, 0, nullptr, false, lc, quad);
        __syncthreads();

        // ---- residual add, commit ----
        c += dl9[w][i] + dl8[w][i];
        ccl[w][i] = c;
        __syncthreads();
    }

    cc_out[w * 64 + i] = c;
}

// ---------------- Phase 2: bf16-MFMA per-slot MLP + max over clusters ----------------
// Round 7: 4 slots per workgroup (256 threads, one slot per wave). Round-6 evidence:
// with 64-thread wg, occupancy self-capped at ~30% regardless of resources (52 VGPR,
// 2.5KB LDS) -> 4096 tiny wg were dispatch/workgroup-slot limited (87 wg/us). 4x fewer,
// 4x bigger wg removes that cap. Also: Wb loads are issued BEFORE the frA pack waits
// on Wa (vmcnt(16) leaves rgB in flight under matmul1+transpose). No barriers needed:
// each wave owns a private hT slab.
#define HSTR 72
#define SLOTS_PER_BLK 4
__global__ __launch_bounds__(256, 4) void phase2_kernel(
    const float* __restrict__ Wa, const float* __restrict__ ba,
    const float* __restrict__ Wb, const float* __restrict__ bb,
    const float* __restrict__ cc, float* __restrict__ out)
{
    const int w = threadIdx.x >> 6;                 // wave id in block
    const int l = threadIdx.x & 63;                 // lane
    const int s = blockIdx.x * SLOTS_PER_BLK + w;   // slot
    const int quad = l >> 4;
    const int lc   = l & 15;

    __shared__ u16 hT[SLOTS_PER_BLK][16 * HSTR];    // per-wave h-transpose slab

    const float* wa = Wa + (size_t)s * 4096;
    const float* wb = Wb + (size_t)s * 4096;

    // ---- B-fragments from cc (2.5 KB broadcast; L2-resident) — issue first ----
    bf16x8 bcc[2];
#pragma unroll
    for (int kt = 0; kt < 2; ++kt) {
        if (lc < NCLU) {
            const float* cp = cc + lc * 64 + kt * 32 + quad * 8;
            bcc[kt] = pack8(*(const float4*)cp, *(const float4*)(cp + 4));
        } else {
#pragma unroll
            for (int j = 0; j < 8; ++j) bcc[kt][j] = 0;
        }
    }

    // ---- ba early (needed right after matmul1) ----
    float4 bav[4];
#pragma unroll
    for (int mt = 0; mt < 4; ++mt)
        bav[mt] = *(const float4*)(ba + s * 64 + 16 * mt + quad * 4);

    // ---- issue Wa loads (16x dwordx4) ----
    float4 rgA[16];
#pragma unroll
    for (int mt = 0; mt < 4; ++mt)
#pragma unroll
        for (int kt = 0; kt < 2; ++kt) {
            const float* p = wa + (16 * mt + lc) * 64 + kt * 32 + quad * 8;
            rgA[(mt * 2 + kt) * 2 + 0] = *(const float4*)p;
            rgA[(mt * 2 + kt) * 2 + 1] = *(const float4*)(p + 4);
        }

    // ---- issue Wb loads (16x dwordx4) BEFORE any wait on Wa ----
    float4 rgB[16];
#pragma unroll
    for (int mt = 0; mt < 4; ++mt)
#pragma unroll
        for (int kt = 0; kt < 2; ++kt) {
            const float* p = wb + (16 * mt + lc) * 64 + kt * 32 + quad * 8;
            rgB[(mt * 2 + kt) * 2 + 0] = *(const float4*)p;
            rgB[(mt * 2 + kt) * 2 + 1] = *(const float4*)(p + 4);
        }

    // ---- pack frA (waits vmcnt for rgA only; rgB stays in flight) ----
    bf16x8 frA[4][2];
#pragma unroll
    for (int mt = 0; mt < 4; ++mt)
#pragma unroll
        for (int kt = 0; kt < 2; ++kt)
            frA[mt][kt] = pack8(rgA[(mt * 2 + kt) * 2], rgA[(mt * 2 + kt) * 2 + 1]);

    // ---- matmul1: h = relu(Wa @ cc^T + ba), D: col=lc (n), row=4quad+r (dim) ----
    f32x4 acc[4];
#pragma unroll
    for (int mt = 0; mt < 4; ++mt) acc[mt] = (f32x4){0.f, 0.f, 0.f, 0.f};
#pragma unroll
    for (int kt = 0; kt < 2; ++kt)
#pragma unroll
        for (int mt = 0; mt < 4; ++mt)
            acc[mt] = __builtin_amdgcn_mfma_f32_16x16x32_bf16(frA[mt][kt], bcc[kt], acc[mt], 0, 0, 0);

    // ---- bias + relu + bf16, transpose through private LDS slab ----
#pragma unroll
    for (int mt = 0; mt < 4; ++mt) {
        u16 h0 = f2bf_rne(fmaxf(acc[mt][0] + bav[mt].x, 0.f));
        u16 h1 = f2bf_rne(fmaxf(acc[mt][1] + bav[mt].y, 0.f));
        u16 h2 = f2bf_rne(fmaxf(acc[mt][2] + bav[mt].z, 0.f));
        u16 h3 = f2bf_rne(fmaxf(acc[mt][3] + bav[mt].w, 0.f));
        uint2 pk; pk.x = (u32)h0 | ((u32)h1 << 16); pk.y = (u32)h2 | ((u32)h3 << 16);
        *(uint2*)(&hT[w][lc * HSTR + 16 * mt + quad * 4]) = pk;
    }

    // ---- pack Wb fragments (rgB arrived during matmul1/transpose) ----
    bf16x8 frB[4][2];
#pragma unroll
    for (int mt = 0; mt < 4; ++mt)
#pragma unroll
        for (int kt = 0; kt < 2; ++kt)
            frB[mt][kt] = pack8(rgB[(mt * 2 + kt) * 2], rgB[(mt * 2 + kt) * 2 + 1]);

    // ---- B-fragments of h from hT (single wave: compiler lgkmcnt orders write->read) ----
    bf16x8 bh[2];
#pragma unroll
    for (int kt = 0; kt < 2; ++kt)
        bh[kt] = *(const bf16x8*)(&hT[w][lc * HSTR + kt * 32 + quad * 8]);

    // ---- matmul2: out_pre = Wb @ h^T ----
    f32x4 acc2[4];
#pragma unroll
    for (int mt = 0; mt < 4; ++mt) acc2[mt] = (f32x4){0.f, 0.f, 0.f, 0.f};
#pragma unroll
    for (int kt = 0; kt < 2; ++kt)
#pragma unroll
        for (int mt = 0; mt < 4; ++mt)
            acc2[mt] = __builtin_amdgcn_mfma_f32_16x16x32_bf16(frB[mt][kt], bh[kt], acc2[mt], 0, 0, 0);

    // ---- max over clusters (cols lc<NCLU), then + bb ----
    const float NEG = -3.0e38f;
#pragma unroll
    for (int mt = 0; mt < 4; ++mt) {
#pragma unroll
        for (int r = 0; r < 4; ++r) {
            float v = (lc < NCLU) ? acc2[mt][r] : NEG;
#pragma unroll
            for (int off = 1; off < 16; off <<= 1)
                v = fmaxf(v, __shfl_xor(v, off));
            acc2[mt][r] = v;
        }
    }

    if (lc < 4) {
#pragma unroll
        for (int mt = 0; mt < 4; ++mt) {
            int row = 16 * mt + 4 * quad + lc;
            out[s * 64 + row] = acc2[mt][lc] + bb[s * 64 + row];
        }
    }
}

extern "C" void kernel_launch(void* const* d_in, const int* in_sizes, int n_in,
                              void* d_out, int out_size, void* d_ws, size_t ws_size,
                              hipStream_t stream) {
    const float* cc0  = (const float*)d_in[0];
    const float* Wk   = (const float*)d_in[1];
    const float* bk   = (const float*)d_in[2];
    const float* Wq   = (const float*)d_in[3];
    const float* bq   = (const float*)d_in[4];
    const float* Wv   = (const float*)d_in[5];
    const float* bv   = (const float*)d_in[6];
    const float* ccg  = (const float*)d_in[7];
    const float* ccb  = (const float*)d_in[8];
    const float* Wih  = (const float*)d_in[9];
    const float* Whh  = (const float*)d_in[10];
    const float* bih  = (const float*)d_in[11];
    const float* bhh  = (const float*)d_in[12];
    const float* lng  = (const float*)d_in[13];
    const float* lnb  = (const float*)d_in[14];
    const float* W1   = (const float*)d_in[15];
    const float* b1   = (const float*)d_in[16];
    const float* W2   = (const float*)d_in[17];
    const float* b2   = (const float*)d_in[18];
    const float* Wa   = (const float*)d_in[19];
    const float* ba   = (const float*)d_in[20];
    const float* Wb   = (const float*)d_in[21];
    const float* bb   = (const float*)d_in[22];

    float* cc_ws = (float*)d_ws;     // 640 floats
    float* out   = (float*)d_out;

    hipLaunchKernelGGL(phase1_kernel, dim3(1), dim3(640), 0, stream,
                       cc0, Wk, bk, Wq, bq, Wv, bv, ccg, ccb,
                       Wih, Whh, bih, bhh, lng, lnb, W1, b1, W2, b2, cc_ws);

    hipLaunchKernelGGL(phase2_kernel, dim3(NSLOT / SLOTS_PER_BLK), dim3(256), 0, stream,
                       Wa, ba, Wb, bb, cc_ws, out);
}

// Round 3
// 214.060 us; speedup vs baseline: 1.0205x; 1.0205x over previous
//
#include <hip/hip_runtime.h>
#include <math.h>

#define NCLU 10
#define D    64
#define NSLOT 4096

typedef unsigned int   u32;
typedef unsigned short u16;

typedef __attribute__((ext_vector_type(8))) short  bf16x8;
typedef __attribute__((ext_vector_type(4))) float  f32x4;

__device__ __forceinline__ u16 f2bf_rne(float f) {
    u32 u = __float_as_uint(f);
    return (u16)((u + 0x7fffu + ((u >> 16) & 1u)) >> 16);
}

__device__ __forceinline__ bf16x8 pack8(float4 a, float4 b) {
    bf16x8 r;
    r[0] = (short)f2bf_rne(a.x); r[1] = (short)f2bf_rne(a.y);
    r[2] = (short)f2bf_rne(a.z); r[3] = (short)f2bf_rne(a.w);
    r[4] = (short)f2bf_rne(b.x); r[5] = (short)f2bf_rne(b.y);
    r[6] = (short)f2bf_rne(b.z); r[7] = (short)f2bf_rne(b.w);
    return r;
}

__device__ __forceinline__ float wred(float v) {
#pragma unroll
    for (int off = 32; off > 0; off >>= 1) v += __shfl_xor(v, off);
    return v;
}

// Load a 64x64 f32 weight matrix as MFMA A-fragments (bf16): a[mt][kt], lane (quad,lc)
// holds W[16*mt+lc][kt*32 + quad*8 .. +7]. 32 VGPRs total per wave.
__device__ __forceinline__ void load_afrags64(bf16x8 a[4][2], const float* __restrict__ W,
                                              int lc, int quad) {
#pragma unroll
    for (int mt = 0; mt < 4; ++mt)
#pragma unroll
        for (int kt = 0; kt < 2; ++kt) {
            const float* p = W + (16 * mt + lc) * 64 + kt * 32 + quad * 8;
            a[mt][kt] = pack8(*(const float4*)p, *(const float4*)(p + 4));
        }
}

// Same for a 64x128 matrix, covering k-tiles ktbase..ktbase+1 (half of K=128).
__device__ __forceinline__ void load_afrags128(bf16x8 a[4][2], const float* __restrict__ W,
                                               int ktbase, int lc, int quad) {
#pragma unroll
    for (int mt = 0; mt < 4; ++mt)
#pragma unroll
        for (int kt = 0; kt < 2; ++kt) {
            const float* p = W + (16 * mt + lc) * 128 + (ktbase + kt) * 32 + quad * 8;
            a[mt][kt] = pack8(*(const float4*)p, *(const float4*)(p + 4));
        }
}

// B-fragment from f32 LDS state X[n][k] (row stride in floats): lane holds
// X[n=lc][ktglob*32 + quad*8 .. +7], zeros for n>=NCLU.
__device__ __forceinline__ bf16x8 bfrag(const float* __restrict__ xbase, int xstride,
                                        int lc, int quad, int ktglob) {
    if (lc < NCLU) {
        const float* p = xbase + lc * xstride + ktglob * 32 + quad * 8;
        return pack8(*(const float4*)p, *(const float4*)(p + 4));
    }
    bf16x8 z;
#pragma unroll
    for (int j = 0; j < 8; ++j) z[j] = 0;
    return z;
}

// D = A(64xK) @ X^T (+bias, opt relu) written to out[n=lc][ooff + dim].
// D layout: col=lane&15 (n), row=quad*4+reg (dim within 16-tile).
__device__ __forceinline__ void mm_apply(const bf16x8 a[4][2], const float* __restrict__ xbase,
                                         int xstride, int ktbase,
                                         float* __restrict__ obase, int ostride, int ooff,
                                         const float* __restrict__ bias, bool do_relu,
                                         int lc, int quad) {
    f32x4 acc[4];
#pragma unroll
    for (int mt = 0; mt < 4; ++mt) acc[mt] = (f32x4){0.f, 0.f, 0.f, 0.f};
#pragma unroll
    for (int kt = 0; kt < 2; ++kt) {
        bf16x8 b = bfrag(xbase, xstride, lc, quad, ktbase + kt);
#pragma unroll
        for (int mt = 0; mt < 4; ++mt)
            acc[mt] = __builtin_amdgcn_mfma_f32_16x16x32_bf16(a[mt][kt], b, acc[mt], 0, 0, 0);
    }
    if (lc < NCLU) {
#pragma unroll
        for (int mt = 0; mt < 4; ++mt) {
            float4 o;
            o.x = acc[mt][0]; o.y = acc[mt][1]; o.z = acc[mt][2]; o.w = acc[mt][3];
            if (bias) {
                float4 bv = *(const float4*)(bias + 16 * mt + 4 * quad);
                o.x += bv.x; o.y += bv.y; o.z += bv.z; o.w += bv.w;
            }
            if (do_relu) {
                o.x = fmaxf(o.x, 0.f); o.y = fmaxf(o.y, 0.f);
                o.z = fmaxf(o.z, 0.f); o.w = fmaxf(o.w, 0.f);
            }
            *(float4*)(obase + lc * ostride + ooff + 16 * mt + 4 * quad) = o;
        }
    }
}

// ---------------- Phase 1: MFMA weight-stationary slot-attention ----------------
// (unchanged — isolating the phase-2 change this round)
__global__ __launch_bounds__(640, 3) void phase1_kernel(
    const float* __restrict__ cc0,
    const float* __restrict__ Wk, const float* __restrict__ bk,
    const float* __restrict__ Wq, const float* __restrict__ bq,
    const float* __restrict__ Wv, const float* __restrict__ bv,
    const float* __restrict__ cc_g, const float* __restrict__ cc_b,
    const float* __restrict__ W_ih, const float* __restrict__ W_hh,
    const float* __restrict__ b_ih, const float* __restrict__ b_hh,
    const float* __restrict__ ln_g, const float* __restrict__ ln_b,
    const float* __restrict__ W1, const float* __restrict__ b1,
    const float* __restrict__ W2, const float* __restrict__ b2,
    float* __restrict__ cc_out)
{
    const int t = threadIdx.x;
    const int w = t >> 6;
    const int i = t & 63;
    const int quad = i >> 4;
    const int lc   = i & 15;

    __shared__ float ccl[NCLU][68];
    __shared__ float xl[NCLU][68];
    __shared__ float kl[NCLU][68];
    __shared__ float vl[NCLU][68];
    __shared__ float ql[NCLU][68];
    __shared__ float ul[NCLU][68];
    __shared__ float hl[NCLU][68];
    __shared__ float dl9[NCLU][68];
    __shared__ float dl8[NCLU][68];
    __shared__ float tl[NCLU][132];
    __shared__ float gl[6][NCLU][68];
    __shared__ float al[NCLU][12];

    const float g_cc = cc_g[i], b_cc = cc_b[i];
    const float g_ln = ln_g[i], b_ln = ln_b[i];

    // ---- weight fragments (per-wave role; arrays are 32 VGPRs each) ----
    bf16x8 afrA[4][2], afrB[4][2];
#pragma unroll
    for (int mt = 0; mt < 4; ++mt)
#pragma unroll
        for (int kt = 0; kt < 2; ++kt) {
#pragma unroll
            for (int j = 0; j < 8; ++j) { afrA[mt][kt][j] = 0; afrB[mt][kt][j] = 0; }
        }

    const float* biasA = nullptr;   // bias pointer for afrA's matmul
    if (w == 0)      { load_afrags64(afrA, Wq, lc, quad);                    biasA = bq; }
    else if (w <= 3) { load_afrags64(afrA, W_ih + (w - 1) * 64 * 64, lc, quad); biasA = b_ih + (w - 1) * 64; }
    else if (w <= 6) { load_afrags64(afrA, W_hh + (w - 4) * 64 * 64, lc, quad); biasA = b_hh + (w - 4) * 64; }
    else if (w == 7) { load_afrags64(afrA, Wk, lc, quad); }   // swapped to W1-lo after kv
    else if (w == 8) { load_afrags64(afrA, Wv, lc, quad);     // swapped to W1-hi after kv
                       load_afrags128(afrB, W2, 2, lc, quad); }
    else             { load_afrags128(afrA, W2, 0, lc, quad); biasA = b2; }

    float c = cc0[w * 64 + i];
    ccl[w][i] = c;
    __syncthreads();

    // ---- k, v from original cluster_centers ----
    if (w == 7)      mm_apply(afrA, &ccl[0][0], 68, 0, &kl[0][0], 68, 0, bk, false, lc, quad);
    else if (w == 8) mm_apply(afrA, &ccl[0][0], 68, 0, &vl[0][0], 68, 0, bv, false, lc, quad);
    __syncthreads();

    // swap w7/w8 to W1 halves (one-time global frag loads, overlap with iter-1 front)
    if (w == 7)      { load_afrags64(afrA, W1, lc, quad);            biasA = b1; }
    else if (w == 8) { load_afrags64(afrA, W1 + 64 * 64, lc, quad);  biasA = b1 + 64; }

    for (int it = 0; it < 3; ++it) {
        // ---- LN(cc) ----
        {
            float s1 = wred(c), s2 = wred(c * c);
            float mu = s1 * (1.f / 64.f);
            float va = s2 * (1.f / 64.f) - mu * mu;
            xl[w][i] = (c - mu) * rsqrtf(va + 1e-5f) * g_cc + b_cc;
        }
        __syncthreads();

        // ---- q (w0, xl) concurrent with gh gates (w4-6, prev ccl) ----
        if (w == 0)
            mm_apply(afrA, &xl[0][0], 68, 0, &ql[0][0], 68, 0, biasA, false, lc, quad);
        else if (w >= 4 && w <= 6)
            mm_apply(afrA, &ccl[0][0], 68, 0, &gl[w - 1][0][0], 68, 0, biasA, false, lc, quad);
        __syncthreads();

        // ---- attn[n][m] = temp * <k[n], q[m]>, wave n, lanes m<10 ----
        if (i < NCLU) {
            const float4* kf = (const float4*)&kl[w][0];
            const float4* qf = (const float4*)&ql[i][0];
            float a0 = 0.f, a1 = 0.f, a2 = 0.f, a3 = 0.f;
#pragma unroll
            for (int jj = 0; jj < 16; ++jj) {
                float4 kv = kf[jj], qv = qf[jj];
                a0 += kv.x * qv.x; a1 += kv.y * qv.y; a2 += kv.z * qv.z; a3 += kv.w * qv.w;
            }
            al[w][i] = ((a0 + a1) + (a2 + a3)) * 0.125f;
        }
        __syncthreads();

        // ---- softmax over axis 0 + EPS ----
        if (t < NCLU) {
            float mx = -1e30f;
#pragma unroll
            for (int nn = 0; nn < NCLU; ++nn) mx = fmaxf(mx, al[nn][t]);
            float e[NCLU]; float s = 0.f;
#pragma unroll
            for (int nn = 0; nn < NCLU; ++nn) { e[nn] = __expf(al[nn][t] - mx); s += e[nn]; }
            float inv = 1.f / s;
#pragma unroll
            for (int nn = 0; nn < NCLU; ++nn) al[nn][t] = e[nn] * inv + 1e-8f;
        }
        __syncthreads();
        // ---- row renormalize ----
        if (t < NCLU) {
            float s = 0.f;
#pragma unroll
            for (int m = 0; m < NCLU; ++m) s += al[t][m];
            float inv = 1.f / s;
#pragma unroll
            for (int m = 0; m < NCLU; ++m) al[t][m] *= inv;
        }
        __syncthreads();

        // ---- updates = attn @ v ----
        {
            float u = 0.f;
#pragma unroll
            for (int m = 0; m < NCLU; ++m) u += al[w][m] * vl[m][i];
            ul[w][i] = u;
        }
        __syncthreads();

        // ---- gi gates (w1-3, from ul) ----
        if (w >= 1 && w <= 3)
            mm_apply(afrA, &ul[0][0], 68, 0, &gl[w - 1][0][0], 68, 0, biasA, false, lc, quad);
        __syncthreads();

        // ---- GRU combine + MLP LN (wave == row) ----
        {
            float ir = gl[0][w][i], iz = gl[1][w][i], inn = gl[2][w][i];
            float hr = gl[3][w][i], hz = gl[4][w][i], hn = gl[5][w][i];
            float r = 1.f / (1.f + __expf(-(ir + hr)));
            float z = 1.f / (1.f + __expf(-(iz + hz)));
            float nn2 = tanhf(inn + r * hn);
            c = (1.f - z) * nn2 + z * c;

            float s1 = wred(c), s2 = wred(c * c);
            float mu = s1 * (1.f / 64.f);
            float va = s2 * (1.f / 64.f) - mu * mu;
            hl[w][i] = (c - mu) * rsqrtf(va + 1e-5f) * g_ln + b_ln;
        }
        __syncthreads();

        // ---- hidden = relu(h @ W1^T + b1): w7 -> tl[:,0:64], w8 -> tl[:,64:128] ----
        if (w == 7)
            mm_apply(afrA, &hl[0][0], 68, 0, &tl[0][0], 132, 0, biasA, true, lc, quad);
        else if (w == 8)
            mm_apply(afrA, &hl[0][0], 68, 0, &tl[0][0], 132, 64, biasA, true, lc, quad);
        __syncthreads();

        // ---- delta = hidden @ W2^T + b2: w9 k[0:64] (+b2), w8 k[64:128] ----
        if (w == 9)
            mm_apply(afrA, &tl[0][0], 132, 0, &dl9[0][0], 68, 0, biasA, false, lc, quad);
        else if (w == 8)
            mm_apply(afrB, &tl[0][0], 132, 2, &dl8[0][0], 68, 0, nullptr, false, lc, quad);
        __syncthreads();

        // ---- residual add, commit ----
        c += dl9[w][i] + dl8[w][i];
        ccl[w][i] = c;
        __syncthreads();
    }

    cc_out[w * 64 + i] = c;
}

// ---------------- Phase 2: bf16-MFMA per-slot MLP + max over clusters ----------------
// Round 8: 4 COOPERATING waves per slot (block = 1 slot, 256 threads). Evidence from
// R0-R2: three structures all stuck at ~47us / 2.8 TB/s effective, VGPR_Count 52-56
// proves the compiler serialized the intended 32-load prefetch (rgA+rgB need ~130
// regs). Fix: per-wave footprint drops to its 16-row output stripe — 4 Wa loads +
// 4 Wb loads + cc + bias fit in registers trivially, ALL issued before any wait.
// 4x the wave count (16384), ~20 waves/CU resident (launch_bounds cap 102 VGPR).
// Cross-wave h exchange through the shared hT slab (one __syncthreads).
#define HSTR 72
__global__ __launch_bounds__(256, 5) void phase2_kernel(
    const float* __restrict__ Wa, const float* __restrict__ ba,
    const float* __restrict__ Wb, const float* __restrict__ bb,
    const float* __restrict__ cc, float* __restrict__ out)
{
    const int w = threadIdx.x >> 6;       // wave id = output-row stripe 16w..16w+15
    const int l = threadIdx.x & 63;
    const int s = blockIdx.x;             // slot
    const int quad = l >> 4;
    const int lc   = l & 15;

    __shared__ u16 hT[16 * HSTR];         // h transposed: [n][dim] bf16, shared by 4 waves

    const float* wa = Wa + (size_t)s * 4096;
    const float* wb = Wb + (size_t)s * 4096;

    // ---- issue ALL global loads up front (fits registers: ~13 VMEM instr) ----
    // cc B-operand rows (lc<NCLU), 4x float4
    float4 c00, c01, c10, c11;
    if (lc < NCLU) {
        const float* cp = cc + lc * 64;
        c00 = *(const float4*)(cp + 0 * 32 + quad * 8);
        c01 = *(const float4*)(cp + 0 * 32 + quad * 8 + 4);
        c10 = *(const float4*)(cp + 1 * 32 + quad * 8);
        c11 = *(const float4*)(cp + 1 * 32 + quad * 8 + 4);
    }
    // Wa stripe: rows 16w+lc, 4x float4
    float4 a00, a01, a10, a11;
    {
        const float* p0 = wa + (16 * w + lc) * 64 + 0 * 32 + quad * 8;
        const float* p1 = wa + (16 * w + lc) * 64 + 1 * 32 + quad * 8;
        a00 = *(const float4*)p0; a01 = *(const float4*)(p0 + 4);
        a10 = *(const float4*)p1; a11 = *(const float4*)(p1 + 4);
    }
    // ba stripe (issued before Wb so waiting for it doesn't drain Wb)
    float4 bav = *(const float4*)(ba + s * 64 + 16 * w + quad * 4);
    // Wb stripe: rows 16w+lc, 4x float4 (in flight across matmul1 + transpose)
    float4 b00, b01, b10, b11;
    {
        const float* p0 = wb + (16 * w + lc) * 64 + 0 * 32 + quad * 8;
        const float* p1 = wb + (16 * w + lc) * 64 + 1 * 32 + quad * 8;
        b00 = *(const float4*)p0; b01 = *(const float4*)(p0 + 4);
        b10 = *(const float4*)p1; b11 = *(const float4*)(p1 + 4);
    }

    // ---- pack A-fragments (Wa) and B-fragments (cc) ----
    bf16x8 frA[2];
    frA[0] = pack8(a00, a01);
    frA[1] = pack8(a10, a11);
    bf16x8 bcc[2];
    if (lc < NCLU) {
        bcc[0] = pack8(c00, c01);
        bcc[1] = pack8(c10, c11);
    } else {
#pragma unroll
        for (int j = 0; j < 8; ++j) { bcc[0][j] = 0; bcc[1][j] = 0; }
    }

    // ---- matmul1: h stripe = relu(Wa[16w..16w+15,:] @ cc^T + ba stripe) ----
    f32x4 acc = (f32x4){0.f, 0.f, 0.f, 0.f};
    acc = __builtin_amdgcn_mfma_f32_16x16x32_bf16(frA[0], bcc[0], acc, 0, 0, 0);
    acc = __builtin_amdgcn_mfma_f32_16x16x32_bf16(frA[1], bcc[1], acc, 0, 0, 0);

    // ---- bias + relu + bf16, transpose into shared hT ----
    {
        u16 h0 = f2bf_rne(fmaxf(acc[0] + bav.x, 0.f));
        u16 h1 = f2bf_rne(fmaxf(acc[1] + bav.y, 0.f));
        u16 h2 = f2bf_rne(fmaxf(acc[2] + bav.z, 0.f));
        u16 h3 = f2bf_rne(fmaxf(acc[3] + bav.w, 0.f));
        uint2 pk; pk.x = (u32)h0 | ((u32)h1 << 16); pk.y = (u32)h2 | ((u32)h3 << 16);
        *(uint2*)(&hT[lc * HSTR + 16 * w + quad * 4]) = pk;
    }

    // ---- pack Wb fragments (loads arrived under matmul1/transpose) ----
    bf16x8 frB[2];
    frB[0] = pack8(b00, b01);
    frB[1] = pack8(b10, b11);

    __syncthreads();   // full h visible to all waves

    // ---- B-fragments of h (full 64 hidden dims) ----
    bf16x8 bh[2];
#pragma unroll
    for (int kt = 0; kt < 2; ++kt)
        bh[kt] = *(const bf16x8*)(&hT[lc * HSTR + kt * 32 + quad * 8]);

    // ---- matmul2: out stripe = Wb[16w..16w+15,:] @ h^T ----
    f32x4 acc2 = (f32x4){0.f, 0.f, 0.f, 0.f};
    acc2 = __builtin_amdgcn_mfma_f32_16x16x32_bf16(frB[0], bh[0], acc2, 0, 0, 0);
    acc2 = __builtin_amdgcn_mfma_f32_16x16x32_bf16(frB[1], bh[1], acc2, 0, 0, 0);

    // ---- max over clusters (cols lc<NCLU), then + bb ----
    const float NEG = -3.0e38f;
#pragma unroll
    for (int r = 0; r < 4; ++r) {
        float v = (lc < NCLU) ? acc2[r] : NEG;
#pragma unroll
        for (int off = 1; off < 16; off <<= 1)
            v = fmaxf(v, __shfl_xor(v, off));
        acc2[r] = v;
    }

    if (lc < 4) {
        int row = 16 * w + 4 * quad + lc;
        out[s * 64 + row] = acc2[lc] + bb[s * 64 + row];
    }
}

extern "C" void kernel_launch(void* const* d_in, const int* in_sizes, int n_in,
                              void* d_out, int out_size, void* d_ws, size_t ws_size,
                              hipStream_t stream) {
    const float* cc0  = (const float*)d_in[0];
    const float* Wk   = (const float*)d_in[1];
    const float* bk   = (const float*)d_in[2];
    const float* Wq   = (const float*)d_in[3];
    const float* bq   = (const float*)d_in[4];
    const float* Wv   = (const float*)d_in[5];
    const float* bv   = (const float*)d_in[6];
    const float* ccg  = (const float*)d_in[7];
    const float* ccb  = (const float*)d_in[8];
    const float* Wih  = (const float*)d_in[9];
    const float* Whh  = (const float*)d_in[10];
    const float* bih  = (const float*)d_in[11];
    const float* bhh  = (const float*)d_in[12];
    const float* lng  = (const float*)d_in[13];
    const float* lnb  = (const float*)d_in[14];
    const float* W1   = (const float*)d_in[15];
    const float* b1   = (const float*)d_in[16];
    const float* W2   = (const float*)d_in[17];
    const float* b2   = (const float*)d_in[18];
    const float* Wa   = (const float*)d_in[19];
    const float* ba   = (const float*)d_in[20];
    const float* Wb   = (const float*)d_in[21];
    const float* bb   = (const float*)d_in[22];

    float* cc_ws = (float*)d_ws;     // 640 floats
    float* out   = (float*)d_out;

    hipLaunchKernelGGL(phase1_kernel, dim3(1), dim3(640), 0, stream,
                       cc0, Wk, bk, Wq, bq, Wv, bv, ccg, ccb,
                       Wih, Whh, bih, bhh, lng, lnb, W1, b1, W2, b2, cc_ws);

    hipLaunchKernelGGL(phase2_kernel, dim3(NSLOT), dim3(256), 0, stream,
                       Wa, ba, Wb, bb, cc_ws, out);
}